// Round 6
// baseline (283.791 us; speedup 1.0000x reference)
//
#include <hip/hip_runtime.h>
#include <hip/hip_bf16.h>

#define BB 4
#define SS 2048
#define DD 1024
#define HH 16
#define MM (BB * SS)   // 8192

typedef __attribute__((ext_vector_type(8))) short bf16x8;
typedef __attribute__((ext_vector_type(4))) float f32x4;

__device__ __forceinline__ unsigned short f2bf(float f) {
  union { float f; unsigned u; } v; v.f = f;
  unsigned r = v.u + 0x7fffu + ((v.u >> 16) & 1u);
  return (unsigned short)(r >> 16);
}

__device__ __forceinline__ void gl2lds16(const void* g, void* l) {
  __builtin_amdgcn_global_load_lds(
      (const __attribute__((address_space(1))) unsigned int*)g,
      (__attribute__((address_space(3))) unsigned int*)l, 16, 0, 0);
}

// fp32 -> bf16 pre-convert: y<4 -> W[y] (1M each), y>=4 -> X chunk (8M total).
// Wq (y==0) is pre-scaled by log2e/8: folds the softmax 1/sqrt(DK) and ln->log2
// conversion into the QKV GEMM's Q output at zero cost (this kernel is HBM-bound).
__global__ __launch_bounds__(256)
void convall(const float* __restrict__ X, const float* __restrict__ a,
             const float* __restrict__ b, const float* __restrict__ c,
             const float* __restrict__ d, unsigned short* __restrict__ wall,
             unsigned short* __restrict__ xb) {
  int y = blockIdx.y;
  const float* s; unsigned short* o; float scl = 1.0f;
  if (y < 4) {
    const float* srcs[4] = {a, b, c, d};
    s = srcs[y]; o = wall + (size_t)y * 1048576;
    if (y == 0) scl = 0.180336880f;   // log2e / 8
  } else {
    s = X + (size_t)(y - 4) * 1048576; o = xb + (size_t)(y - 4) * 1048576;
  }
  int i = (blockIdx.x * 256 + threadIdx.x) * 4;
  float4 v = *(const float4*)(s + i);
  ushort4 h4;
  h4.x = f2bf(v.x * scl); h4.y = f2bf(v.y * scl);
  h4.z = f2bf(v.z * scl); h4.w = f2bf(v.w * scl);
  *(ushort4*)(o + i) = h4;
}

// C[m,n] = sum_k A[m,k]*W[n,k].  A bf16, B bf16, both staged via global_load_lds w=16.
// R6: T3+T4 — 3-buffer LDS pipeline, prefetch depth 2, COUNTED vmcnt (never 0 in
// the main loop).  Per K-step: {s_waitcnt vmcnt(4) [batch t done, batch t+1 still
// in flight] -> raw s_barrier -> STAGE(t+2) -> ds_read buf[t] + MFMA}.  The
// __syncthreads() full vmcnt(0) drain (the m97-structure ~20% stall) is gone.
// Safety: staging buf (t+2)%3 overwrites buf (t-1)%3, whose ds_reads drained via
// the compiler's lgkmcnt before MFMA use, hence before barrier arrival.
// OMODE 1: fp32 C.  OMODE 3: QKV routing (Q bf16 / K bf16 / V -> sigma-permuted V^T,
// Vt[bh][d][kt*64 + sigma(key)], sigma(key) = (key&15)*4 + (key>>4)).
template<int OMODE>
__global__ __launch_bounds__(256)
void gemm_k(const unsigned short* __restrict__ A16, const unsigned short* __restrict__ Bp,
            void* __restrict__ C0p, void* __restrict__ C1p, void* __restrict__ C2p) {
  __shared__ unsigned short As[3 * 4096];  // 3-buf staging [128][32]; also V^T transpose buf
  __shared__ unsigned short Bs[3 * 4096];
  const int m0 = blockIdx.x * 128, n0g = blockIdx.y * 128;
  const int tid = threadIdx.x, lane = tid & 63, wave = tid >> 6;
  const int wm = (wave & 1) * 64, wn = (wave >> 1) * 64;
  const int row_in = lane & 15, quad = lane >> 4;

  f32x4 acc[4][4] = {};

  // staging source pointers (advance by kb shorts per K-step)
  const int r = wave * 32 + (lane >> 2);
  const unsigned short* gB = Bp + (size_t)(n0g + r) * DD + (lane & 3) * 8;
  const unsigned short* gA = A16 + (size_t)(m0 + r) * DD + (lane & 3) * 8;
  const int wrow0 = (wave * 32) * 32, wrow1 = (wave * 32 + 16) * 32;

#define STAGE_G(t, bo)                                         \
  do {                                                         \
    const int kb_ = (t) * 32;                                  \
    gl2lds16(gB + kb_, Bs + (bo) + wrow0);                     \
    gl2lds16(gB + kb_ + (size_t)16 * DD, Bs + (bo) + wrow1);   \
    gl2lds16(gA + kb_, As + (bo) + wrow0);                     \
    gl2lds16(gA + kb_ + (size_t)16 * DD, As + (bo) + wrow1);   \
  } while (0)

  // prologue: stage t=0 -> buf0, t=1 -> buf1
  STAGE_G(0, 0);
  STAGE_G(1, 4096);

  int bo_rd = 0;        // buffer holding tile t
  int bo_st = 8192;     // buffer for tile t+2
  const int NT = DD / 32;
  for (int t = 0; t < NT; ++t) {
    // batch t complete (4 newest loads may remain in flight); no full drain
    if (t < NT - 1) {
      asm volatile("s_waitcnt vmcnt(4)" ::: "memory");
    } else {
      asm volatile("s_waitcnt vmcnt(0)" ::: "memory");
    }
    __builtin_amdgcn_s_barrier();
    if (t + 2 < NT) STAGE_G(t + 2, bo_st);
    bf16x8 af[4], bfr[4];
#pragma unroll
    for (int i = 0; i < 4; ++i)
      af[i] = *(const bf16x8*)(As + bo_rd + (wm + i * 16 + row_in) * 32 + quad * 8);
#pragma unroll
    for (int j = 0; j < 4; ++j)
      bfr[j] = *(const bf16x8*)(Bs + bo_rd + (wn + j * 16 + row_in) * 32 + quad * 8);
    __builtin_amdgcn_s_setprio(1);
#pragma unroll
    for (int i = 0; i < 4; ++i)
#pragma unroll
      for (int j = 0; j < 4; ++j)
        acc[i][j] = __builtin_amdgcn_mfma_f32_16x16x32_bf16(af[i], bfr[j], acc[i][j], 0, 0, 0);
    __builtin_amdgcn_s_setprio(0);
    bo_rd = (bo_rd == 8192) ? 0 : bo_rd + 4096;
    bo_st = (bo_st == 8192) ? 0 : bo_st + 4096;
  }
#undef STAGE_G
  __syncthreads();   // all reads of As/Bs done before epilogue (Ts aliases As)

  // C/D layout: col = lane&15, row = quad*4 + reg
  if (OMODE == 1) {
    float* Cout = (float*)C0p;
#pragma unroll
    for (int i = 0; i < 4; ++i)
#pragma unroll
      for (int j = 0; j < 4; ++j)
#pragma unroll
        for (int r2 = 0; r2 < 4; ++r2)
          Cout[(size_t)(m0 + wm + i * 16 + quad * 4 + r2) * DD + n0g + wn + j * 16 + row_in] =
              acc[i][j][r2];
  } else {
    const int seg = n0g >> 10;
    if (seg < 2) {
      unsigned short* Cout = (unsigned short*)(seg == 0 ? C0p : C1p);
      const int n0 = n0g & 1023;
#pragma unroll
      for (int i = 0; i < 4; ++i)
#pragma unroll
        for (int j = 0; j < 4; ++j)
#pragma unroll
          for (int r2 = 0; r2 < 4; ++r2)
            Cout[(size_t)(m0 + wm + i * 16 + quad * 4 + r2) * DD + n0 + wn + j * 16 + row_in] =
                f2bf(acc[i][j][r2]);
    } else {
      // V^T epilogue -> Vt[bh][d][kt*64 + sigma(key)].  Stored position p holds
      // key sigma^-1(p) = (p&3)*16 + (p>>2): gather cols from the transpose buffer.
      unsigned short* Vt = (unsigned short*)C2p;
      unsigned short* Ts = As;
      const int b = m0 >> 11, m_in_b = m0 & 2047;
      const int nv = n0g - 2048;
#pragma unroll
      for (int cn = 0; cn < 4; ++cn) {
        if ((wave >> 1) == (cn >> 1)) {
#pragma unroll
          for (int i = 0; i < 4; ++i)
#pragma unroll
            for (int jj = 0; jj < 2; ++jj)
#pragma unroll
              for (int r2 = 0; r2 < 4; ++r2) {
                int j = (cn & 1) * 2 + jj;
                Ts[(jj * 16 + row_in) * 136 + wm + i * 16 + quad * 4 + r2] = f2bf(acc[i][j][r2]);
              }
        }
        __syncthreads();
#pragma unroll
        for (int it = 0; it < 2; ++it) {
          int cc = tid + it * 256;
          int rowL = cc >> 4, o8 = (cc & 15) * 8;
          int cbase = rowL * 136 + (o8 & 64) + ((o8 & 63) >> 2);
          ushort4 lo, hi;
          lo.x = Ts[cbase];      lo.y = Ts[cbase + 16];
          lo.z = Ts[cbase + 32]; lo.w = Ts[cbase + 48];
          hi.x = Ts[cbase + 1];  hi.y = Ts[cbase + 17];
          hi.z = Ts[cbase + 33]; hi.w = Ts[cbase + 49];
          int n = nv + cn * 32 + rowL;
          int h = n >> 6, dd = n & 63;
          unsigned short* dst = Vt + ((size_t)((b * 16 + h) * 64 + dd)) * SS + m_in_b + o8;
          *(ushort4*)dst = lo;
          *(ushort4*)(dst + 4) = hi;
        }
        __syncthreads();
      }
    }
  }
}

// Flash attention R4 shell (unchanged): 128 q-rows/block, 4 waves x 32 q, 4 blocks/CU.
// Q arrives pre-scaled by log2e/8 (folded into Wq in convall); p = exp2(sacc) directly.
// P->bf16 pack via bias-add + v_perm (NOT inline-asm cvt_pk: m240 measured -37%).
// V sigma-pre-permuted in global; wave-private P stripes; AO in-place over Q.
__global__ __launch_bounds__(256, 4)
void attn_kernel(const unsigned short* __restrict__ Q, const unsigned short* __restrict__ K,
                 const unsigned short* __restrict__ Vt_g, unsigned short* __restrict__ AO) {
  __shared__ unsigned short Ks[64 * 72];   // [key][d]
  __shared__ unsigned short Vs[64 * 72];   // [d][sigma(key)]
  __shared__ unsigned short Ps[128 * 72];  // [q perm][sigma(key)]
  // linear dispatch id (x-fastest); xcd = L&7 is the HW round-robin slot.
  // qt = j&15, bh = (L&7) + 8*(j>>4)  (bijective; all qt of a bh share L mod 8)
  const int L = (blockIdx.y << 4) + blockIdx.x;
  const int jj = L >> 3;
  const int qt = jj & 15;
  const int bh = (L & 7) + ((jj >> 4) << 3);
  const int b = bh >> 4, h = bh & 15;
  const int tid = threadIdx.x, lane = tid & 63, w = tid >> 6;
  const int row_in = lane & 15, quad = lane >> 4;
  const size_t qbase = ((size_t)(b * SS + qt * 128)) * DD + h * 64;

  bf16x8 aq[2][2];
#pragma unroll
  for (int m = 0; m < 2; ++m) {
    const unsigned short* qp = Q + qbase + (size_t)(w * 32 + m * 16 + row_in) * DD;
    aq[m][0] = *(const bf16x8*)(qp + quad * 8);
    aq[m][1] = *(const bf16x8*)(qp + 32 + quad * 8);
  }
  f32x4 oacc[2][4] = {};
  float lrow[2][4] = {};
  const int permr = 2 * (row_in >> 2) + (row_in & 1) + 8 * ((row_in >> 1) & 1);
  const int pw_base = (w * 32) * 72;

  // staging coords (thread-invariant): chunk c -> r = c>>3, o8 = (c&7)*8
  const int r0 = tid >> 3, o80 = (tid & 7) * 8;
  const int r1 = (tid + 256) >> 3, o81 = o80;  // (tid+256)&7 == tid&7
  const unsigned short* kp0 = K + ((size_t)(b * SS + r0)) * DD + h * 64 + o80;
  const unsigned short* kp1 = K + ((size_t)(b * SS + r1)) * DD + h * 64 + o81;
  const unsigned short* vp0 = Vt_g + ((size_t)(bh * 64 + r0)) * SS + o80;
  const unsigned short* vp1 = Vt_g + ((size_t)(bh * 64 + r1)) * SS + o81;

  // prologue prefetch kt=0
  uint4 kr0 = *(const uint4*)kp0;
  uint4 kr1 = *(const uint4*)kp1;
  uint4 vr0 = *(const uint4*)vp0;
  uint4 vr1 = *(const uint4*)vp1;

  for (int kt = 0; kt < SS / 64; ++kt) {
    __syncthreads();               // all waves done reading Ks/Vs of kt-1
    *(uint4*)(Ks + r0 * 72 + o80) = kr0;
    *(uint4*)(Ks + r1 * 72 + o81) = kr1;
    *(uint4*)(Vs + r0 * 72 + o80) = vr0;
    *(uint4*)(Vs + r1 * 72 + o81) = vr1;
    __syncthreads();               // staging visible
    if (kt + 1 < SS / 64) {
      // issue kt+1 loads now; they fly under the whole compute phase
      const size_t ko = (size_t)(kt + 1) * 64 * DD;
      const size_t vo = (size_t)(kt + 1) * 64;
      kr0 = *(const uint4*)(kp0 + ko);
      kr1 = *(const uint4*)(kp1 + ko);
      vr0 = *(const uint4*)(vp0 + vo);
      vr1 = *(const uint4*)(vp1 + vo);
    }

    // S = Q K^T : 32q x 64key per wave (Q carries the log2e/8 scale)
    f32x4 sacc[2][4] = {};
    __builtin_amdgcn_s_setprio(1);
#pragma unroll
    for (int n = 0; n < 4; ++n) {
      bf16x8 bk0 = *(const bf16x8*)(Ks + (n * 16 + row_in) * 72 + quad * 8);
      bf16x8 bk1 = *(const bf16x8*)(Ks + (n * 16 + row_in) * 72 + 32 + quad * 8);
#pragma unroll
      for (int m = 0; m < 2; ++m) {
        sacc[m][n] = __builtin_amdgcn_mfma_f32_16x16x32_bf16(aq[m][0], bk0, sacc[m][n], 0, 0, 0);
        sacc[m][n] = __builtin_amdgcn_mfma_f32_16x16x32_bf16(aq[m][1], bk1, sacc[m][n], 0, 0, 0);
      }
    }
    __builtin_amdgcn_s_setprio(0);

    // softmax: p = exp2(s); writer's keys {n*16+row_in} land at sigma = row_in*4+n
    // -> one b64 write per (m,r)
#pragma unroll
    for (int m = 0; m < 2; ++m)
#pragma unroll
      for (int r = 0; r < 4; ++r) {
        int prow = pw_base + (m * 16 + 2 * quad + (r & 1) + 8 * ((r >> 1) & 1)) * 72;
        union { float f; unsigned u; } p0, p1, p2, p3;
        p0.f = __builtin_amdgcn_exp2f(sacc[m][0][r]);
        p1.f = __builtin_amdgcn_exp2f(sacc[m][1][r]);
        p2.f = __builtin_amdgcn_exp2f(sacc[m][2][r]);
        p3.f = __builtin_amdgcn_exp2f(sacc[m][3][r]);
        lrow[m][r] += (p0.f + p1.f) + (p2.f + p3.f);
        unsigned w01 = __builtin_amdgcn_perm(p1.u + 0x8000u, p0.u + 0x8000u, 0x07060302);
        unsigned w23 = __builtin_amdgcn_perm(p3.u + 0x8000u, p2.u + 0x8000u, 0x07060302);
        *(uint2*)(Ps + prow + row_in * 4) = make_uint2(w01, w23);
      }

    // O += P V over sigma-space (wave-private P rows -> no barrier)
    __builtin_amdgcn_s_setprio(1);
#pragma unroll
    for (int c = 0; c < 2; ++c) {
      bf16x8 ap0 = *(const bf16x8*)(Ps + pw_base + (permr) * 72 + c * 32 + quad * 8);
      bf16x8 ap1 = *(const bf16x8*)(Ps + pw_base + (16 + permr) * 72 + c * 32 + quad * 8);
#pragma unroll
      for (int t = 0; t < 4; ++t) {
        bf16x8 bv = *(const bf16x8*)(Vs + (t * 16 + row_in) * 72 + c * 32 + quad * 8);
        oacc[0][t] = __builtin_amdgcn_mfma_f32_16x16x32_bf16(ap0, bv, oacc[0][t], 0, 0, 0);
        oacc[1][t] = __builtin_amdgcn_mfma_f32_16x16x32_bf16(ap1, bv, oacc[1][t], 0, 0, 0);
      }
    }
    __builtin_amdgcn_s_setprio(0);
  }

#pragma unroll
  for (int m = 0; m < 2; ++m)
#pragma unroll
    for (int r = 0; r < 4; ++r) {
#pragma unroll
      for (int s = 1; s < 16; s <<= 1) lrow[m][r] += __shfl_xor(lrow[m][r], s, 64);
      float inv = 1.0f / lrow[m][r];
#pragma unroll
      for (int t = 0; t < 4; ++t)
        AO[qbase + (size_t)(w * 32 + m * 16 + quad * 4 + r) * DD + t * 16 + row_in] =
            f2bf(oacc[m][t][r] * inv);
    }
}

extern "C" void kernel_launch(void* const* d_in, const int* in_sizes, int n_in,
                              void* d_out, int out_size, void* d_ws, size_t ws_size,
                              hipStream_t stream) {
  const float* X  = (const float*)d_in[0];
  const float* Wq = (const float*)d_in[1];
  const float* Wk = (const float*)d_in[2];
  const float* Wv = (const float*)d_in[3];
  const float* Wo = (const float*)d_in[4];

  unsigned short* ws   = (unsigned short*)d_ws;
  unsigned short* Qb   = ws;                           // 16 MiB — also AO
  unsigned short* Kb   = Qb + (size_t)MM * DD;         // 16 MiB
  unsigned short* Vtb  = Kb + (size_t)MM * DD;         // 16 MiB, [bh][d][sigma(s)]
  unsigned short* Wall = Vtb + (size_t)MM * DD;        // 8 MiB (Wq,Wk,Wv,Wo bf16)
  unsigned short* Xb   = (unsigned short*)d_out;       // 16 MiB scratch inside d_out
  float* out = (float*)d_out;

  convall<<<dim3(1024, 12), 256, 0, stream>>>(X, Wq, Wk, Wv, Wo, Wall, Xb);

  gemm_k<3><<<dim3(MM / 128, 24), 256, 0, stream>>>(Xb, Wall, Qb, Kb, Vtb);

  attn_kernel<<<dim3(SS / 128, BB * HH), 256, 0, stream>>>(Qb, Kb, Vtb, Qb);

  gemm_k<1><<<dim3(MM / 128, 8), 256, 0, stream>>>(Qb, Wall + (size_t)3 * 1048576,
                                                   out, nullptr, nullptr);
}

// Round 7
// 265.516 us; speedup vs baseline: 1.0688x; 1.0688x over previous
//
#include <hip/hip_runtime.h>
#include <hip/hip_bf16.h>

#define BB 4
#define SS 2048
#define DD 1024
#define HH 16
#define MM (BB * SS)   // 8192

typedef __attribute__((ext_vector_type(8))) short bf16x8;
typedef __attribute__((ext_vector_type(4))) float f32x4;

__device__ __forceinline__ unsigned short f2bf(float f) {
  union { float f; unsigned u; } v; v.f = f;
  unsigned r = v.u + 0x7fffu + ((v.u >> 16) & 1u);
  return (unsigned short)(r >> 16);
}

__device__ __forceinline__ void gl2lds16(const void* g, void* l) {
  __builtin_amdgcn_global_load_lds(
      (const __attribute__((address_space(1))) unsigned int*)g,
      (__attribute__((address_space(3))) unsigned int*)l, 16, 0, 0);
}

// fp32 -> bf16 pre-convert: y<4 -> W[y] (1M each), y>=4 -> X chunk (8M total).
// Wq (y==0) pre-scaled by log2e/8 (softmax scale folded into Q at zero cost).
__global__ __launch_bounds__(256)
void convall(const float* __restrict__ X, const float* __restrict__ a,
             const float* __restrict__ b, const float* __restrict__ c,
             const float* __restrict__ d, unsigned short* __restrict__ wall,
             unsigned short* __restrict__ xb) {
  int y = blockIdx.y;
  const float* s; unsigned short* o; float scl = 1.0f;
  if (y < 4) {
    const float* srcs[4] = {a, b, c, d};
    s = srcs[y]; o = wall + (size_t)y * 1048576;
    if (y == 0) scl = 0.180336880f;   // log2e / 8
  } else {
    s = X + (size_t)(y - 4) * 1048576; o = xb + (size_t)(y - 4) * 1048576;
  }
  int i = (blockIdx.x * 256 + threadIdx.x) * 4;
  float4 v = *(const float4*)(s + i);
  ushort4 h4;
  h4.x = f2bf(v.x * scl); h4.y = f2bf(v.y * scl);
  h4.z = f2bf(v.z * scl); h4.w = f2bf(v.w * scl);
  *(ushort4*)(o + i) = h4;
}

// ---------------------------------------------------------------------------
// R7: 256x256 8-phase GEMM (guide Sec.5 template, T2+T3+T4+T5 co-designed).
// C[m,n] = sum_k A[m,k]*W[n,k], bf16 in, bf16 out routed {Q,K,V} by n-range.
// 512 thr (8 waves, 2M x 4N), BK=64, 128KB dyn LDS: 2 bufs x (A[256][64]+B[256][64]).
// T2 swizzle: phys chunk = logical ^ (row&7); global_load_lds dest LINEAR,
// SOURCE inverse-swizzled per lane (rule #21), reads XOR on the fly.
// Phase schedule (per iter i: read tiles 2i/buf0 ph1-4, 2i+1/buf1 ph5-8;
// k-slice/m-half quadrants (k0,mL)(k0,mU)(k1,mL)(k1,mU)):
//   stages: ph1 SB(t+1->buf1) ph2 SA1(t+1) ph4 SA0(t+2->buf0) ph5 SB(t+2)
//           ph6 SA1(t+2) ph8 SA0(t+3->buf1)
//   counted waits (derived FIFO coverage, never 0): ph1 vmcnt(4), ph2 vmcnt(6),
//           ph5 vmcnt(4), ph6 vmcnt(6).
// Last-iter stages clamp the SOURCE tile to 15 (dest slots provably dead) so
// all 8 iterations are uniform, incl. waits. Prologue order [A0,B,A1,t1.A0]
// makes steady-state waits valid at iter 0.
// ---------------------------------------------------------------------------
__global__ __launch_bounds__(512, 2)
void gemm256(const unsigned short* __restrict__ A16, const unsigned short* __restrict__ Bp,
             unsigned short* __restrict__ Qo, unsigned short* __restrict__ Ko,
             unsigned short* __restrict__ Vo) {
  extern __shared__ unsigned short L[];   // 65536 shorts = 128 KB
  // XCD-bijective remap: 384 blocks = 8 XCD x 48
  const int Lid = blockIdx.x;
  const int wg = (Lid & 7) * 48 + (Lid >> 3);
  const int mx = wg & 31, ny = wg >> 5;
  const int m0 = mx * 256, n0g = ny * 256;

  const int tid = threadIdx.x, lane = tid & 63, wv = tid >> 6;
  const int wave_m = wv >> 2, wave_n = wv & 3;
  const int row_in = lane & 15, quad = lane >> 4;

  // staging lane constants: phys slot (row = l>>3, chunk = l&7) holds logical
  // chunk (l&7)^(l>>3) -> per-lane inverse-swizzled source offset
  const int srow = lane >> 3;
  const int sc = ((lane & 7) ^ (lane >> 3)) * 8;
  const unsigned short* gA0 = A16 + (size_t)(m0 + srow) * DD + sc;
  const unsigned short* gB0 = Bp + (size_t)(n0g + srow) * DD + sc;

  // read lane constants (R&7 == row_in&7 for all frags)
  const int aoff = (wave_m * 128 + row_in) * 64;
  const int boff = (wave_n * 64 + row_in) * 64;
  const int swz0 = ((quad) ^ (row_in & 7)) * 8;
  const int swz1 = ((4 + quad) ^ (row_in & 7)) * 8;

  f32x4 acc[8][4] = {};

#define SA(a, par, kbv)                                                         \
  do {                                                                          \
    const int ld_ = (par) * 16384 + (a) * 8192 + (wv * 16) * 64;                \
    gl2lds16(gA0 + (size_t)((a) * 128 + wv * 16 + 0) * DD + (kbv), L + ld_);    \
    gl2lds16(gA0 + (size_t)((a) * 128 + wv * 16 + 8) * DD + (kbv), L + ld_ + 512); \
  } while (0)
#define SBf(par, kbv)                                                           \
  do {                                                                          \
    const int ld_ = 32768 + (par) * 16384 + (wv * 32) * 64;                     \
    gl2lds16(gB0 + (size_t)(wv * 32 + 0) * DD + (kbv), L + ld_);                \
    gl2lds16(gB0 + (size_t)(wv * 32 + 8) * DD + (kbv), L + ld_ + 512);          \
    gl2lds16(gB0 + (size_t)(wv * 32 + 16) * DD + (kbv), L + ld_ + 1024);        \
    gl2lds16(gB0 + (size_t)(wv * 32 + 24) * DD + (kbv), L + ld_ + 1536);        \
  } while (0)
#define LDA(par, mh, swzv)                                                      \
  do {                                                                          \
    _Pragma("unroll") for (int f = 0; f < 4; ++f)                               \
        af[f] = *(const bf16x8*)(L + (par) * 16384 + aoff + ((mh) * 64 + f * 16) * 64 + (swzv)); \
  } while (0)
#define LDB(par, swzv)                                                          \
  do {                                                                          \
    _Pragma("unroll") for (int nf = 0; nf < 4; ++nf)                            \
        bk[nf] = *(const bf16x8*)(L + 32768 + (par) * 16384 + boff + nf * 1024 + (swzv)); \
  } while (0)
#define MFMA16(mh)                                                              \
  do {                                                                          \
    __builtin_amdgcn_s_setprio(1);                                              \
    _Pragma("unroll") for (int f = 0; f < 4; ++f)                               \
        _Pragma("unroll") for (int nf = 0; nf < 4; ++nf)                        \
            acc[(mh) * 4 + f][nf] = __builtin_amdgcn_mfma_f32_16x16x32_bf16(    \
                af[f], bk[nf], acc[(mh) * 4 + f][nf], 0, 0, 0);                 \
    __builtin_amdgcn_s_setprio(0);                                              \
  } while (0)
#define PBAR()                                 \
  do {                                         \
    asm volatile("" ::: "memory");             \
    __builtin_amdgcn_s_barrier();              \
    asm volatile("" ::: "memory");             \
  } while (0)
#define PWAIT(n) asm volatile("s_waitcnt vmcnt(" #n ")" ::: "memory")

  // prologue: [t0.A0, t0.B, t0.A1, t1.A0]  (FIFO order makes iter-0 waits valid)
  SA(0, 0, 0);
  SBf(0, 0);
  SA(1, 0, 0);
  SA(0, 1, 64);

  for (int i = 0; i < 8; ++i) {
    const int kb1 = (2 * i + 1) * 64;
    const int t2 = 2 * i + 2, t3 = 2 * i + 3;
    const int kb2 = (t2 < 16 ? t2 : 15) * 64;   // clamped source; dest slot dead
    const int kb3 = (t3 < 16 ? t3 : 15) * 64;
    bf16x8 af[4], bk[4];
    // ph1 (k0,mL buf0)
    PWAIT(4); PBAR();
    LDB(0, swz0); LDA(0, 0, swz0);
    SBf(1, kb1);
    MFMA16(0);
    // ph2 (k0,mU)
    PWAIT(6); PBAR();
    LDA(0, 1, swz0);
    SA(1, 1, kb1);
    MFMA16(1);
    // ph3 (k1,mL)
    PBAR();
    LDB(0, swz1); LDA(0, 0, swz1);
    MFMA16(0);
    // ph4 (k1,mU)
    PBAR();
    LDA(0, 1, swz1);
    SA(0, 0, kb2);
    MFMA16(1);
    // ph5 (k0,mL buf1)
    PWAIT(4); PBAR();
    LDB(1, swz0); LDA(1, 0, swz0);
    SBf(0, kb2);
    MFMA16(0);
    // ph6 (k0,mU)
    PWAIT(6); PBAR();
    LDA(1, 1, swz0);
    SA(1, 0, kb2);
    MFMA16(1);
    // ph7 (k1,mL)
    PBAR();
    LDB(1, swz1); LDA(1, 0, swz1);
    MFMA16(0);
    // ph8 (k1,mU)
    PBAR();
    LDA(1, 1, swz1);
    SA(0, 1, kb3);
    MFMA16(1);
  }
  asm volatile("s_waitcnt vmcnt(0)" ::: "memory");  // drain garbage stages
#undef SA
#undef SBf
#undef LDA
#undef LDB
#undef MFMA16
#undef PBAR
#undef PWAIT

  // epilogue: bf16 write, route by n-range (n0g multiple of 256; 1024-aligned segs)
  const int seg = n0g >> 10;
  unsigned short* Cout = (seg == 0) ? Qo : (seg == 1) ? Ko : Vo;
  const int n0 = n0g & 1023;
#pragma unroll
  for (int mh = 0; mh < 2; ++mh)
#pragma unroll
    for (int f = 0; f < 4; ++f)
#pragma unroll
      for (int nf = 0; nf < 4; ++nf)
#pragma unroll
        for (int r2 = 0; r2 < 4; ++r2)
          Cout[(size_t)(m0 + wave_m * 128 + mh * 64 + f * 16 + quad * 4 + r2) * DD +
               n0 + wave_n * 64 + nf * 16 + row_in] = f2bf(acc[mh * 4 + f][nf][r2]);
}

// V -> Vt[bh][d][kt*64 + sigma(key)]; stored position p holds key (p&3)*16+(p>>2).
// Pure memory op (~32MB), replaces the in-GEMM V^T epilogue.
__global__ __launch_bounds__(256)
void vtrans(const unsigned short* __restrict__ V, unsigned short* __restrict__ Vt) {
  __shared__ unsigned short T[64][66];
  const int kt = blockIdx.x, bh = blockIdx.y, b = bh >> 4, h = bh & 15;
  const int t = threadIdx.x;
  const unsigned short* src = V + ((size_t)(b * SS + kt * 64)) * DD + h * 64;
#pragma unroll
  for (int it = 0; it < 2; ++it) {
    int key = (t >> 3) + it * 32, c8 = (t & 7) * 8;
    *(uint4*)&T[key][c8] = *(const uint4*)(src + (size_t)key * DD + c8);
  }
  __syncthreads();
#pragma unroll
  for (int it = 0; it < 4; ++it) {
    int d = (t >> 4) + it * 16, pc = t & 15;   // p = pc*4 + j -> key = j*16 + pc
    ushort4 v;
    v.x = T[pc + 0][d];
    v.y = T[pc + 16][d];
    v.z = T[pc + 32][d];
    v.w = T[pc + 48][d];
    *(ushort4*)(Vt + ((size_t)(bh * 64 + d)) * SS + kt * 64 + pc * 4) = v;
  }
}

// O-projection GEMM: R5 128x128 2-phase dbuf structure (proven), fp32 out.
__global__ __launch_bounds__(256)
void gemm_o(const unsigned short* __restrict__ A16, const unsigned short* __restrict__ Bp,
            float* __restrict__ Cout) {
  __shared__ unsigned short As[2 * 4096];
  __shared__ unsigned short Bs[2 * 4096];
  const int m0 = blockIdx.x * 128, n0g = blockIdx.y * 128;
  const int tid = threadIdx.x, lane = tid & 63, wave = tid >> 6;
  const int wm = (wave & 1) * 64, wn = (wave >> 1) * 64;
  const int row_in = lane & 15, quad = lane >> 4;

  f32x4 acc[4][4] = {};

  const int r = wave * 32 + (lane >> 2);
  const unsigned short* gB = Bp + (size_t)(n0g + r) * DD + (lane & 3) * 8;
  const unsigned short* gA = A16 + (size_t)(m0 + r) * DD + (lane & 3) * 8;

  gl2lds16(gB, Bs + (wave * 32) * 32);
  gl2lds16(gB + (size_t)16 * DD, Bs + (wave * 32 + 16) * 32);
  gl2lds16(gA, As + (wave * 32) * 32);
  gl2lds16(gA + (size_t)16 * DD, As + (wave * 32 + 16) * 32);

  int cur = 0;
  for (int kb = 0; kb < DD; kb += 32) {
    __syncthreads();
    if (kb + 32 < DD) {
      const int nx = (cur ^ 1) * 4096;
      gl2lds16(gB + kb + 32, Bs + nx + (wave * 32) * 32);
      gl2lds16(gB + kb + 32 + (size_t)16 * DD, Bs + nx + (wave * 32 + 16) * 32);
      gl2lds16(gA + kb + 32, As + nx + (wave * 32) * 32);
      gl2lds16(gA + kb + 32 + (size_t)16 * DD, As + nx + (wave * 32 + 16) * 32);
    }
    const int cb = cur * 4096;
    bf16x8 af[4], bfr[4];
#pragma unroll
    for (int i = 0; i < 4; ++i)
      af[i] = *(const bf16x8*)(As + cb + (wm + i * 16 + row_in) * 32 + quad * 8);
#pragma unroll
    for (int j = 0; j < 4; ++j)
      bfr[j] = *(const bf16x8*)(Bs + cb + (wn + j * 16 + row_in) * 32 + quad * 8);
    __builtin_amdgcn_s_setprio(1);
#pragma unroll
    for (int i = 0; i < 4; ++i)
#pragma unroll
      for (int j = 0; j < 4; ++j)
        acc[i][j] = __builtin_amdgcn_mfma_f32_16x16x32_bf16(af[i], bfr[j], acc[i][j], 0, 0, 0);
    __builtin_amdgcn_s_setprio(0);
    cur ^= 1;
  }
  __syncthreads();

#pragma unroll
  for (int i = 0; i < 4; ++i)
#pragma unroll
    for (int j = 0; j < 4; ++j)
#pragma unroll
      for (int r2 = 0; r2 < 4; ++r2)
        Cout[(size_t)(m0 + wm + i * 16 + quad * 4 + r2) * DD + n0g + wn + j * 16 + row_in] =
            acc[i][j][r2];
}

// Flash attention (R4 shell, unchanged; 93 us): 128 q-rows/block, 4 waves x 32 q,
// 4 blocks/CU; XCD remap; reg-prefetch K/V; p = exp2(sacc); bias-add+v_perm pack.
__global__ __launch_bounds__(256, 4)
void attn_kernel(const unsigned short* __restrict__ Q, const unsigned short* __restrict__ K,
                 const unsigned short* __restrict__ Vt_g, unsigned short* __restrict__ AO) {
  __shared__ unsigned short Ks[64 * 72];   // [key][d]
  __shared__ unsigned short Vs[64 * 72];   // [d][sigma(key)]
  __shared__ unsigned short Ps[128 * 72];  // [q perm][sigma(key)]
  const int L = (blockIdx.y << 4) + blockIdx.x;
  const int jj = L >> 3;
  const int qt = jj & 15;
  const int bh = (L & 7) + ((jj >> 4) << 3);
  const int b = bh >> 4, h = bh & 15;
  const int tid = threadIdx.x, lane = tid & 63, w = tid >> 6;
  const int row_in = lane & 15, quad = lane >> 4;
  const size_t qbase = ((size_t)(b * SS + qt * 128)) * DD + h * 64;

  bf16x8 aq[2][2];
#pragma unroll
  for (int m = 0; m < 2; ++m) {
    const unsigned short* qp = Q + qbase + (size_t)(w * 32 + m * 16 + row_in) * DD;
    aq[m][0] = *(const bf16x8*)(qp + quad * 8);
    aq[m][1] = *(const bf16x8*)(qp + 32 + quad * 8);
  }
  f32x4 oacc[2][4] = {};
  float lrow[2][4] = {};
  const int permr = 2 * (row_in >> 2) + (row_in & 1) + 8 * ((row_in >> 1) & 1);
  const int pw_base = (w * 32) * 72;

  const int r0 = tid >> 3, o80 = (tid & 7) * 8;
  const int r1 = (tid + 256) >> 3, o81 = o80;
  const unsigned short* kp0 = K + ((size_t)(b * SS + r0)) * DD + h * 64 + o80;
  const unsigned short* kp1 = K + ((size_t)(b * SS + r1)) * DD + h * 64 + o81;
  const unsigned short* vp0 = Vt_g + ((size_t)(bh * 64 + r0)) * SS + o80;
  const unsigned short* vp1 = Vt_g + ((size_t)(bh * 64 + r1)) * SS + o81;

  uint4 kr0 = *(const uint4*)kp0;
  uint4 kr1 = *(const uint4*)kp1;
  uint4 vr0 = *(const uint4*)vp0;
  uint4 vr1 = *(const uint4*)vp1;

  for (int kt = 0; kt < SS / 64; ++kt) {
    __syncthreads();
    *(uint4*)(Ks + r0 * 72 + o80) = kr0;
    *(uint4*)(Ks + r1 * 72 + o81) = kr1;
    *(uint4*)(Vs + r0 * 72 + o80) = vr0;
    *(uint4*)(Vs + r1 * 72 + o81) = vr1;
    __syncthreads();
    if (kt + 1 < SS / 64) {
      const size_t ko = (size_t)(kt + 1) * 64 * DD;
      const size_t vo = (size_t)(kt + 1) * 64;
      kr0 = *(const uint4*)(kp0 + ko);
      kr1 = *(const uint4*)(kp1 + ko);
      vr0 = *(const uint4*)(vp0 + vo);
      vr1 = *(const uint4*)(vp1 + vo);
    }

    f32x4 sacc[2][4] = {};
    __builtin_amdgcn_s_setprio(1);
#pragma unroll
    for (int n = 0; n < 4; ++n) {
      bf16x8 bk0 = *(const bf16x8*)(Ks + (n * 16 + row_in) * 72 + quad * 8);
      bf16x8 bk1 = *(const bf16x8*)(Ks + (n * 16 + row_in) * 72 + 32 + quad * 8);
#pragma unroll
      for (int m = 0; m < 2; ++m) {
        sacc[m][n] = __builtin_amdgcn_mfma_f32_16x16x32_bf16(aq[m][0], bk0, sacc[m][n], 0, 0, 0);
        sacc[m][n] = __builtin_amdgcn_mfma_f32_16x16x32_bf16(aq[m][1], bk1, sacc[m][n], 0, 0, 0);
      }
    }
    __builtin_amdgcn_s_setprio(0);

#pragma unroll
    for (int m = 0; m < 2; ++m)
#pragma unroll
      for (int r = 0; r < 4; ++r) {
        int prow = pw_base + (m * 16 + 2 * quad + (r & 1) + 8 * ((r >> 1) & 1)) * 72;
        union { float f; unsigned u; } p0, p1, p2, p3;
        p0.f = __builtin_amdgcn_exp2f(sacc[m][0][r]);
        p1.f = __builtin_amdgcn_exp2f(sacc[m][1][r]);
        p2.f = __builtin_amdgcn_exp2f(sacc[m][2][r]);
        p3.f = __builtin_amdgcn_exp2f(sacc[m][3][r]);
        lrow[m][r] += (p0.f + p1.f) + (p2.f + p3.f);
        unsigned w01 = __builtin_amdgcn_perm(p1.u + 0x8000u, p0.u + 0x8000u, 0x07060302);
        unsigned w23 = __builtin_amdgcn_perm(p3.u + 0x8000u, p2.u + 0x8000u, 0x07060302);
        *(uint2*)(Ps + prow + row_in * 4) = make_uint2(w01, w23);
      }

    __builtin_amdgcn_s_setprio(1);
#pragma unroll
    for (int c = 0; c < 2; ++c) {
      bf16x8 ap0 = *(const bf16x8*)(Ps + pw_base + (permr) * 72 + c * 32 + quad * 8);
      bf16x8 ap1 = *(const bf16x8*)(Ps + pw_base + (16 + permr) * 72 + c * 32 + quad * 8);
#pragma unroll
      for (int t = 0; t < 4; ++t) {
        bf16x8 bv = *(const bf16x8*)(Vs + (t * 16 + row_in) * 72 + c * 32 + quad * 8);
        oacc[0][t] = __builtin_amdgcn_mfma_f32_16x16x32_bf16(ap0, bv, oacc[0][t], 0, 0, 0);
        oacc[1][t] = __builtin_amdgcn_mfma_f32_16x16x32_bf16(ap1, bv, oacc[1][t], 0, 0, 0);
      }
    }
    __builtin_amdgcn_s_setprio(0);
  }

#pragma unroll
  for (int m = 0; m < 2; ++m)
#pragma unroll
    for (int r = 0; r < 4; ++r) {
#pragma unroll
      for (int s = 1; s < 16; s <<= 1) lrow[m][r] += __shfl_xor(lrow[m][r], s, 64);
      float inv = 1.0f / lrow[m][r];
#pragma unroll
      for (int t = 0; t < 4; ++t)
        AO[qbase + (size_t)(w * 32 + m * 16 + quad * 4 + r) * DD + t * 16 + row_in] =
            f2bf(oacc[m][t][r] * inv);
    }
}

extern "C" void kernel_launch(void* const* d_in, const int* in_sizes, int n_in,
                              void* d_out, int out_size, void* d_ws, size_t ws_size,
                              hipStream_t stream) {
  const float* X  = (const float*)d_in[0];
  const float* Wq = (const float*)d_in[1];
  const float* Wk = (const float*)d_in[2];
  const float* Wv = (const float*)d_in[3];
  const float* Wo = (const float*)d_in[4];

  unsigned short* ws   = (unsigned short*)d_ws;
  unsigned short* Qb   = ws;                           // 16 MiB — also AO
  unsigned short* Kb   = Qb + (size_t)MM * DD;         // 16 MiB
  unsigned short* Vtb  = Kb + (size_t)MM * DD;         // 16 MiB, [bh][d][sigma(s)]
  unsigned short* Wall = Vtb + (size_t)MM * DD;        // 8 MiB (Wq,Wk,Wv,Wo bf16)
  unsigned short* Xb   = (unsigned short*)d_out;                 // 16 MiB scratch (d_out lo)
  unsigned short* Vb   = (unsigned short*)d_out + (size_t)MM * DD; // 16 MiB scratch (d_out hi)
  float* out = (float*)d_out;

  static int inited = 0;
  if (!inited) {
    hipFuncSetAttribute((const void*)gemm256,
                        hipFuncAttributeMaxDynamicSharedMemorySize, 131072);
    inited = 1;
  }

  convall<<<dim3(1024, 12), 256, 0, stream>>>(X, Wq, Wk, Wv, Wo, Wall, Xb);

  gemm256<<<dim3(384), 512, 131072, stream>>>(Xb, Wall, Qb, Kb, Vb);

  vtrans<<<dim3(SS / 64, BB * HH), 256, 0, stream>>>(Vb, Vtb);

  attn_kernel<<<dim3(SS / 128, BB * HH), 256, 0, stream>>>(Qb, Kb, Vtb, Qb);

  gemm_o<<<dim3(MM / 128, 8), 256, 0, stream>>>(Qb, Wall + (size_t)3 * 1048576, out);
}

// Round 10
// 259.449 us; speedup vs baseline: 1.0938x; 1.0234x over previous
//
#include <hip/hip_runtime.h>
#include <hip/hip_bf16.h>

#define BB 4
#define SS 2048
#define DD 1024
#define HH 16
#define MM (BB * SS)   // 8192

typedef __attribute__((ext_vector_type(8))) short bf16x8;
typedef __attribute__((ext_vector_type(4))) float f32x4;

__device__ __forceinline__ unsigned short f2bf(float f) {
  union { float f; unsigned u; } v; v.f = f;
  unsigned r = v.u + 0x7fffu + ((v.u >> 16) & 1u);
  return (unsigned short)(r >> 16);
}

__device__ __forceinline__ void gl2lds16(const void* g, void* l) {
  __builtin_amdgcn_global_load_lds(
      (const __attribute__((address_space(1))) unsigned int*)g,
      (__attribute__((address_space(3))) unsigned int*)l, 16, 0, 0);
}

// fp32 -> bf16 pre-convert: y<4 -> W[y] (1M each), y>=4 -> X chunk (8M total).
// Wq (y==0) pre-scaled by log2e/8 (softmax scale folded into Q at zero cost).
__global__ __launch_bounds__(256)
void convall(const float* __restrict__ X, const float* __restrict__ a,
             const float* __restrict__ b, const float* __restrict__ c,
             const float* __restrict__ d, unsigned short* __restrict__ wall,
             unsigned short* __restrict__ xb) {
  int y = blockIdx.y;
  const float* s; unsigned short* o; float scl = 1.0f;
  if (y < 4) {
    const float* srcs[4] = {a, b, c, d};
    s = srcs[y]; o = wall + (size_t)y * 1048576;
    if (y == 0) scl = 0.180336880f;   // log2e / 8
  } else {
    s = X + (size_t)(y - 4) * 1048576; o = xb + (size_t)(y - 4) * 1048576;
  }
  int i = (blockIdx.x * 256 + threadIdx.x) * 4;
  float4 v = *(const float4*)(s + i);
  ushort4 h4;
  h4.x = f2bf(v.x * scl); h4.y = f2bf(v.y * scl);
  h4.z = f2bf(v.z * scl); h4.w = f2bf(v.w * scl);
  *(ushort4*)(o + i) = h4;
}

// ---------------------------------------------------------------------------
// R10: 256x256 8-phase GEMM (T2+T3+T4+T5) with fused sigma-V^T epilogue.
// C[m,n] = sum_k A[m,k]*W[n,k], bf16 in; n<1024 -> Q, n<2048 -> K,
// n>=2048 -> Vt[bh][d][kt*64 + sigma(key)] written DIRECTLY from registers:
// with key = f*16 + quad*4 + r2, sigma(key) = (key&15)*4 + (key>>4)
//   = 16*quad + 4*r2 + f  -> each lane's 16 values per (mh,nf) are CONTIGUOUS
// in sigma space (two uint4 stores, no LDS transpose, no extra kernel).
// Bit-identical to the R7 vtrans path (same f2bf bits, same coordinates).
// Schedule (verified R7): per iter read tiles 2i/buf0 ph1-4, 2i+1/buf1 ph5-8;
// stages ph1 SB(t+1) ph2 SA1(t+1) ph4 SA0(t+2) ph5 SB(t+2) ph6 SA1(t+2)
// ph8 SA0(t+3); counted waits vmcnt(4)/(6) at ph1/2/5/6, never 0 in-loop.
// T2 swizzle: linear LDS dest + inverse-swizzled global SOURCE (rule #21),
// reads XOR on the fly.  Last-iter stages clamp source tile to 15 (dead slots).
// ---------------------------------------------------------------------------
__global__ __launch_bounds__(512, 2)
void gemm256(const unsigned short* __restrict__ A16, const unsigned short* __restrict__ Bp,
             unsigned short* __restrict__ Qo, unsigned short* __restrict__ Ko,
             unsigned short* __restrict__ Vt) {
  extern __shared__ unsigned short L[];   // 65536 shorts = 128 KB
  // XCD-bijective remap: 384 blocks = 8 XCD x 48
  const int Lid = blockIdx.x;
  const int wg = (Lid & 7) * 48 + (Lid >> 3);
  const int mx = wg & 31, ny = wg >> 5;
  const int m0 = mx * 256, n0g = ny * 256;

  const int tid = threadIdx.x, lane = tid & 63, wv = tid >> 6;
  const int wave_m = wv >> 2, wave_n = wv & 3;
  const int row_in = lane & 15, quad = lane >> 4;

  // staging lane constants: phys slot (row = l>>3, chunk = l&7) holds logical
  // chunk (l&7)^(l>>3) -> per-lane inverse-swizzled source offset
  const int srow = lane >> 3;
  const int sc = ((lane & 7) ^ (lane >> 3)) * 8;
  const unsigned short* gA0 = A16 + (size_t)(m0 + srow) * DD + sc;
  const unsigned short* gB0 = Bp + (size_t)(n0g + srow) * DD + sc;

  // read lane constants (R&7 == row_in&7 for all frags)
  const int aoff = (wave_m * 128 + row_in) * 64;
  const int boff = (wave_n * 64 + row_in) * 64;
  const int swz0 = ((quad) ^ (row_in & 7)) * 8;
  const int swz1 = ((4 + quad) ^ (row_in & 7)) * 8;

  f32x4 acc[8][4] = {};

#define SA(a, par, kbv)                                                         \
  do {                                                                          \
    const int ld_ = (par) * 16384 + (a) * 8192 + (wv * 16) * 64;                \
    gl2lds16(gA0 + (size_t)((a) * 128 + wv * 16 + 0) * DD + (kbv), L + ld_);    \
    gl2lds16(gA0 + (size_t)((a) * 128 + wv * 16 + 8) * DD + (kbv), L + ld_ + 512); \
  } while (0)
#define SBf(par, kbv)                                                           \
  do {                                                                          \
    const int ld_ = 32768 + (par) * 16384 + (wv * 32) * 64;                     \
    gl2lds16(gB0 + (size_t)(wv * 32 + 0) * DD + (kbv), L + ld_);                \
    gl2lds16(gB0 + (size_t)(wv * 32 + 8) * DD + (kbv), L + ld_ + 512);          \
    gl2lds16(gB0 + (size_t)(wv * 32 + 16) * DD + (kbv), L + ld_ + 1024);        \
    gl2lds16(gB0 + (size_t)(wv * 32 + 24) * DD + (kbv), L + ld_ + 1536);        \
  } while (0)
#define LDA(par, mh, swzv)                                                      \
  do {                                                                          \
    _Pragma("unroll") for (int f = 0; f < 4; ++f)                               \
        af[f] = *(const bf16x8*)(L + (par) * 16384 + aoff + ((mh) * 64 + f * 16) * 64 + (swzv)); \
  } while (0)
#define LDB(par, swzv)                                                          \
  do {                                                                          \
    _Pragma("unroll") for (int nf = 0; nf < 4; ++nf)                            \
        bk[nf] = *(const bf16x8*)(L + 32768 + (par) * 16384 + boff + nf * 1024 + (swzv)); \
  } while (0)
#define MFMA16(mh)                                                              \
  do {                                                                          \
    __builtin_amdgcn_s_setprio(1);                                              \
    _Pragma("unroll") for (int f = 0; f < 4; ++f)                               \
        _Pragma("unroll") for (int nf = 0; nf < 4; ++nf)                        \
            acc[(mh) * 4 + f][nf] = __builtin_amdgcn_mfma_f32_16x16x32_bf16(    \
                af[f], bk[nf], acc[(mh) * 4 + f][nf], 0, 0, 0);                 \
    __builtin_amdgcn_s_setprio(0);                                              \
  } while (0)
#define PBAR()                                 \
  do {                                         \
    asm volatile("" ::: "memory");             \
    __builtin_amdgcn_s_barrier();              \
    asm volatile("" ::: "memory");             \
  } while (0)
#define PWAIT(n) asm volatile("s_waitcnt vmcnt(" #n ")" ::: "memory")

  // prologue: [t0.A0, t0.B, t0.A1, t1.A0]  (FIFO order makes iter-0 waits valid)
  SA(0, 0, 0);
  SBf(0, 0);
  SA(1, 0, 0);
  SA(0, 1, 64);

  for (int i = 0; i < 8; ++i) {
    const int kb1 = (2 * i + 1) * 64;
    const int t2 = 2 * i + 2, t3 = 2 * i + 3;
    const int kb2 = (t2 < 16 ? t2 : 15) * 64;   // clamped source; dest slot dead
    const int kb3 = (t3 < 16 ? t3 : 15) * 64;
    bf16x8 af[4], bk[4];
    // ph1 (k0,mL buf0)
    PWAIT(4); PBAR();
    LDB(0, swz0); LDA(0, 0, swz0);
    SBf(1, kb1);
    MFMA16(0);
    // ph2 (k0,mU)
    PWAIT(6); PBAR();
    LDA(0, 1, swz0);
    SA(1, 1, kb1);
    MFMA16(1);
    // ph3 (k1,mL)
    PBAR();
    LDB(0, swz1); LDA(0, 0, swz1);
    MFMA16(0);
    // ph4 (k1,mU)
    PBAR();
    LDA(0, 1, swz1);
    SA(0, 0, kb2);
    MFMA16(1);
    // ph5 (k0,mL buf1)
    PWAIT(4); PBAR();
    LDB(1, swz0); LDA(1, 0, swz0);
    SBf(0, kb2);
    MFMA16(0);
    // ph6 (k0,mU)
    PWAIT(6); PBAR();
    LDA(1, 1, swz0);
    SA(1, 0, kb2);
    MFMA16(1);
    // ph7 (k1,mL)
    PBAR();
    LDB(1, swz1); LDA(1, 0, swz1);
    MFMA16(0);
    // ph8 (k1,mU)
    PBAR();
    LDA(1, 1, swz1);
    SA(0, 1, kb3);
    MFMA16(1);
  }
  asm volatile("s_waitcnt vmcnt(0)" ::: "memory");  // drain garbage stages
#undef SA
#undef SBf
#undef LDA
#undef LDB
#undef MFMA16
#undef PBAR
#undef PWAIT

  // epilogue
  const int seg = n0g >> 10;
  if (seg < 2) {
    unsigned short* Cout = (seg == 0) ? Qo : Ko;
    const int n0 = n0g & 1023;
#pragma unroll
    for (int mh = 0; mh < 2; ++mh)
#pragma unroll
      for (int f = 0; f < 4; ++f)
#pragma unroll
        for (int nf = 0; nf < 4; ++nf)
#pragma unroll
          for (int r2 = 0; r2 < 4; ++r2)
            Cout[(size_t)(m0 + wave_m * 128 + mh * 64 + f * 16 + quad * 4 + r2) * DD +
                 n0 + wave_n * 64 + nf * 16 + row_in] = f2bf(acc[mh * 4 + f][nf][r2]);
  } else {
    // sigma-V^T from registers: m is the key axis, n is the d axis.
    // key-in-tile = f*16 + quad*4 + r2 -> sigma = 16*quad + 4*r2 + f.
    const int b = m0 >> 11;
    const int ktb = ((m0 & 2047) >> 6) + wave_m * 2;
    const int h = ((n0g - 2048) >> 6) + wave_n;
#pragma unroll
    for (int mh = 0; mh < 2; ++mh) {
      const int kt = ktb + mh;
#pragma unroll
      for (int nf = 0; nf < 4; ++nf) {
        unsigned short v[16];
#pragma unroll
        for (int j = 0; j < 16; ++j)
          v[j] = f2bf(acc[mh * 4 + (j & 3)][nf][j >> 2]);
        unsigned short* dst = Vt + ((size_t)((b * 16 + h) * 64 + nf * 16 + row_in)) * SS +
                              kt * 64 + quad * 16;
        *(uint4*)dst = *(const uint4*)v;
        *(uint4*)(dst + 8) = *(const uint4*)(v + 8);
      }
    }
  }
}

// O-projection GEMM: R5 128x128 2-phase dbuf structure (proven), fp32 out.
__global__ __launch_bounds__(256)
void gemm_o(const unsigned short* __restrict__ A16, const unsigned short* __restrict__ Bp,
            float* __restrict__ Cout) {
  __shared__ unsigned short As[2 * 4096];
  __shared__ unsigned short Bs[2 * 4096];
  const int m0 = blockIdx.x * 128, n0g = blockIdx.y * 128;
  const int tid = threadIdx.x, lane = tid & 63, wave = tid >> 6;
  const int wm = (wave & 1) * 64, wn = (wave >> 1) * 64;
  const int row_in = lane & 15, quad = lane >> 4;

  f32x4 acc[4][4] = {};

  const int r = wave * 32 + (lane >> 2);
  const unsigned short* gB = Bp + (size_t)(n0g + r) * DD + (lane & 3) * 8;
  const unsigned short* gA = A16 + (size_t)(m0 + r) * DD + (lane & 3) * 8;

  gl2lds16(gB, Bs + (wave * 32) * 32);
  gl2lds16(gB + (size_t)16 * DD, Bs + (wave * 32 + 16) * 32);
  gl2lds16(gA, As + (wave * 32) * 32);
  gl2lds16(gA + (size_t)16 * DD, As + (wave * 32 + 16) * 32);

  int cur = 0;
  for (int kb = 0; kb < DD; kb += 32) {
    __syncthreads();
    if (kb + 32 < DD) {
      const int nx = (cur ^ 1) * 4096;
      gl2lds16(gB + kb + 32, Bs + nx + (wave * 32) * 32);
      gl2lds16(gB + kb + 32 + (size_t)16 * DD, Bs + nx + (wave * 32 + 16) * 32);
      gl2lds16(gA + kb + 32, As + nx + (wave * 32) * 32);
      gl2lds16(gA + kb + 32 + (size_t)16 * DD, As + nx + (wave * 32 + 16) * 32);
    }
    const int cb = cur * 4096;
    bf16x8 af[4], bfr[4];
#pragma unroll
    for (int i = 0; i < 4; ++i)
      af[i] = *(const bf16x8*)(As + cb + (wm + i * 16 + row_in) * 32 + quad * 8);
#pragma unroll
    for (int j = 0; j < 4; ++j)
      bfr[j] = *(const bf16x8*)(Bs + cb + (wn + j * 16 + row_in) * 32 + quad * 8);
    __builtin_amdgcn_s_setprio(1);
#pragma unroll
    for (int i = 0; i < 4; ++i)
#pragma unroll
      for (int j = 0; j < 4; ++j)
        acc[i][j] = __builtin_amdgcn_mfma_f32_16x16x32_bf16(af[i], bfr[j], acc[i][j], 0, 0, 0);
    __builtin_amdgcn_s_setprio(0);
    cur ^= 1;
  }
  __syncthreads();

#pragma unroll
  for (int i = 0; i < 4; ++i)
#pragma unroll
    for (int j = 0; j < 4; ++j)
#pragma unroll
      for (int r2 = 0; r2 < 4; ++r2)
        Cout[(size_t)(m0 + wm + i * 16 + quad * 4 + r2) * DD + n0g + wn + j * 16 + row_in] =
            acc[i][j][r2];
}

// Flash attention (R4 shell, proven): 128 q-rows/block, 4 waves x 32 q, 4 blocks/CU;
// XCD remap; reg-prefetch K/V; p = exp2(sacc) (scale folded into Q).
// P->bf16 pack: proven bias-add + v_perm (R9 lesson: switching to RNE cvt_pk
// changed P rounding and pushed boundary elements past tolerance — keep the
// round-half-up idiom the passing rounds used).
__global__ __launch_bounds__(256, 4)
void attn_kernel(const unsigned short* __restrict__ Q, const unsigned short* __restrict__ K,
                 const unsigned short* __restrict__ Vt_g, unsigned short* __restrict__ AO) {
  __shared__ unsigned short Ks[64 * 72];   // [key][d]
  __shared__ unsigned short Vs[64 * 72];   // [d][sigma(key)]
  __shared__ unsigned short Ps[128 * 72];  // [q perm][sigma(key)]
  const int L = (blockIdx.y << 4) + blockIdx.x;
  const int jj = L >> 3;
  const int qt = jj & 15;
  const int bh = (L & 7) + ((jj >> 4) << 3);
  const int b = bh >> 4, h = bh & 15;
  const int tid = threadIdx.x, lane = tid & 63, w = tid >> 6;
  const int row_in = lane & 15, quad = lane >> 4;
  const size_t qbase = ((size_t)(b * SS + qt * 128)) * DD + h * 64;

  bf16x8 aq[2][2];
#pragma unroll
  for (int m = 0; m < 2; ++m) {
    const unsigned short* qp = Q + qbase + (size_t)(w * 32 + m * 16 + row_in) * DD;
    aq[m][0] = *(const bf16x8*)(qp + quad * 8);
    aq[m][1] = *(const bf16x8*)(qp + 32 + quad * 8);
  }
  f32x4 oacc[2][4] = {};
  float lrow[2][4] = {};
  const int permr = 2 * (row_in >> 2) + (row_in & 1) + 8 * ((row_in >> 1) & 1);
  const int pw_base = (w * 32) * 72;

  const int r0 = tid >> 3, o80 = (tid & 7) * 8;
  const int r1 = (tid + 256) >> 3, o81 = o80;
  const unsigned short* kp0 = K + ((size_t)(b * SS + r0)) * DD + h * 64 + o80;
  const unsigned short* kp1 = K + ((size_t)(b * SS + r1)) * DD + h * 64 + o81;
  const unsigned short* vp0 = Vt_g + ((size_t)(bh * 64 + r0)) * SS + o80;
  const unsigned short* vp1 = Vt_g + ((size_t)(bh * 64 + r1)) * SS + o81;

  uint4 kr0 = *(const uint4*)kp0;
  uint4 kr1 = *(const uint4*)kp1;
  uint4 vr0 = *(const uint4*)vp0;
  uint4 vr1 = *(const uint4*)vp1;

  for (int kt = 0; kt < SS / 64; ++kt) {
    __syncthreads();
    *(uint4*)(Ks + r0 * 72 + o80) = kr0;
    *(uint4*)(Ks + r1 * 72 + o81) = kr1;
    *(uint4*)(Vs + r0 * 72 + o80) = vr0;
    *(uint4*)(Vs + r1 * 72 + o81) = vr1;
    __syncthreads();
    if (kt + 1 < SS / 64) {
      const size_t ko = (size_t)(kt + 1) * 64 * DD;
      const size_t vo = (size_t)(kt + 1) * 64;
      kr0 = *(const uint4*)(kp0 + ko);
      kr1 = *(const uint4*)(kp1 + ko);
      vr0 = *(const uint4*)(vp0 + vo);
      vr1 = *(const uint4*)(vp1 + vo);
    }

    f32x4 sacc[2][4] = {};
    __builtin_amdgcn_s_setprio(1);
#pragma unroll
    for (int n = 0; n < 4; ++n) {
      bf16x8 bk0 = *(const bf16x8*)(Ks + (n * 16 + row_in) * 72 + quad * 8);
      bf16x8 bk1 = *(const bf16x8*)(Ks + (n * 16 + row_in) * 72 + 32 + quad * 8);
#pragma unroll
      for (int m = 0; m < 2; ++m) {
        sacc[m][n] = __builtin_amdgcn_mfma_f32_16x16x32_bf16(aq[m][0], bk0, sacc[m][n], 0, 0, 0);
        sacc[m][n] = __builtin_amdgcn_mfma_f32_16x16x32_bf16(aq[m][1], bk1, sacc[m][n], 0, 0, 0);
      }
    }
    __builtin_amdgcn_s_setprio(0);

#pragma unroll
    for (int m = 0; m < 2; ++m)
#pragma unroll
      for (int r = 0; r < 4; ++r) {
        int prow = pw_base + (m * 16 + 2 * quad + (r & 1) + 8 * ((r >> 1) & 1)) * 72;
        union { float f; unsigned u; } p0, p1, p2, p3;
        p0.f = __builtin_amdgcn_exp2f(sacc[m][0][r]);
        p1.f = __builtin_amdgcn_exp2f(sacc[m][1][r]);
        p2.f = __builtin_amdgcn_exp2f(sacc[m][2][r]);
        p3.f = __builtin_amdgcn_exp2f(sacc[m][3][r]);
        lrow[m][r] += (p0.f + p1.f) + (p2.f + p3.f);
        unsigned w01 = __builtin_amdgcn_perm(p1.u + 0x8000u, p0.u + 0x8000u, 0x07060302);
        unsigned w23 = __builtin_amdgcn_perm(p3.u + 0x8000u, p2.u + 0x8000u, 0x07060302);
        *(uint2*)(Ps + prow + row_in * 4) = make_uint2(w01, w23);
      }

    __builtin_amdgcn_s_setprio(1);
#pragma unroll
    for (int c = 0; c < 2; ++c) {
      bf16x8 ap0 = *(const bf16x8*)(Ps + pw_base + (permr) * 72 + c * 32 + quad * 8);
      bf16x8 ap1 = *(const bf16x8*)(Ps + pw_base + (16 + permr) * 72 + c * 32 + quad * 8);
#pragma unroll
      for (int t = 0; t < 4; ++t) {
        bf16x8 bv = *(const bf16x8*)(Vs + (t * 16 + row_in) * 72 + c * 32 + quad * 8);
        oacc[0][t] = __builtin_amdgcn_mfma_f32_16x16x32_bf16(ap0, bv, oacc[0][t], 0, 0, 0);
        oacc[1][t] = __builtin_amdgcn_mfma_f32_16x16x32_bf16(ap1, bv, oacc[1][t], 0, 0, 0);
      }
    }
    __builtin_amdgcn_s_setprio(0);
  }

#pragma unroll
  for (int m = 0; m < 2; ++m)
#pragma unroll
    for (int r = 0; r < 4; ++r) {
#pragma unroll
      for (int s = 1; s < 16; s <<= 1) lrow[m][r] += __shfl_xor(lrow[m][r], s, 64);
      float inv = 1.0f / lrow[m][r];
#pragma unroll
      for (int t = 0; t < 4; ++t)
        AO[qbase + (size_t)(w * 32 + m * 16 + quad * 4 + r) * DD + t * 16 + row_in] =
            f2bf(oacc[m][t][r] * inv);
    }
}

extern "C" void kernel_launch(void* const* d_in, const int* in_sizes, int n_in,
                              void* d_out, int out_size, void* d_ws, size_t ws_size,
                              hipStream_t stream) {
  const float* X  = (const float*)d_in[0];
  const float* Wq = (const float*)d_in[1];
  const float* Wk = (const float*)d_in[2];
  const float* Wv = (const float*)d_in[3];
  const float* Wo = (const float*)d_in[4];

  unsigned short* ws   = (unsigned short*)d_ws;
  unsigned short* Qb   = ws;                           // 16 MiB — also AO
  unsigned short* Kb   = Qb + (size_t)MM * DD;         // 16 MiB
  unsigned short* Vtb  = Kb + (size_t)MM * DD;         // 16 MiB, [bh][d][sigma(s)]
  unsigned short* Wall = Vtb + (size_t)MM * DD;        // 8 MiB (Wq,Wk,Wv,Wo bf16)
  unsigned short* Xb   = (unsigned short*)d_out;       // 16 MiB scratch (d_out lo)
  float* out = (float*)d_out;

  static int inited = 0;
  if (!inited) {
    (void)hipFuncSetAttribute((const void*)gemm256,
                              hipFuncAttributeMaxDynamicSharedMemorySize, 131072);
    inited = 1;
  }

  convall<<<dim3(1024, 12), 256, 0, stream>>>(X, Wq, Wk, Wv, Wo, Wall, Xb);

  gemm256<<<dim3(384), 512, 131072, stream>>>(Xb, Wall, Qb, Kb, Vtb);

  attn_kernel<<<dim3(SS / 128, BB * HH), 256, 0, stream>>>(Qb, Kb, Vtb, Qb);

  gemm_o<<<dim3(MM / 128, 8), 256, 0, stream>>>(Qb, Wall + (size_t)3 * 1048576, out);
}